// Round 3
// baseline (862.470 us; speedup 1.0000x reference)
//
#include <hip/hip_runtime.h>
#include <hip/hip_bf16.h>

// Problem constants
constexpr int Bn  = 128;   // batch
constexpr int Ln  = 200;   // sentences
constexpr int D2n = 1024;  // 2*SH
constexpr int G3n = 1536;  // 3*EH
constexpr int Tn  = 3;
constexpr int Nn  = 512;   // A (attention dim) == d_proj cols
constexpr int Kn  = 1024;  // d_proj K

// ---------------------------------------------------------------------------
// gather last_back = sent[:, 0, 512:1024]
__global__ void k_gather_lastb(const float* __restrict__ sent, float* __restrict__ lastb) {
  int i = blockIdx.x * 256 + threadIdx.x;        // 65536 = 128*512
  int b = i >> 9, k = i & 511;
  lastb[i] = sent[(size_t)b * (Ln * D2n) + 512 + k];
}

// ---------------------------------------------------------------------------
// small GEMM: out[b,j] = act(bias[j] + sum_k in[b,k] * W[j,k])
// in: fp32 (B x K), W: fp32 (J x K), bias: fp32, out: fp32 (B x J)
// grid: (J/64, B/16), block 256. Thread: j = bx*64 + tid%64, 4 batches each.
template<int K, int ACT>
__launch_bounds__(256)
__global__ void k_small_gemm(const float* __restrict__ in, const float* __restrict__ W,
                             const float* __restrict__ bias, float* __restrict__ out, int J) {
  __shared__ float s[16 * K];
  const int b0 = blockIdx.y * 16;
  const int jl = threadIdx.x & 63;
  const int j  = blockIdx.x * 64 + jl;
  const int bg = (threadIdx.x >> 6) * 4;         // 0,4,8,12

  const float4* inp4 = (const float4*)(in + (size_t)b0 * K);
  float4* s4 = (float4*)s;
  for (int i = threadIdx.x; i < 4 * K; i += 256) s4[i] = inp4[i];
  __syncthreads();

  const float4* w4 = (const float4*)(W + (size_t)j * K);
  const float4* r0 = (const float4*)(s + (size_t)(bg + 0) * K);
  const float4* r1 = (const float4*)(s + (size_t)(bg + 1) * K);
  const float4* r2 = (const float4*)(s + (size_t)(bg + 2) * K);
  const float4* r3 = (const float4*)(s + (size_t)(bg + 3) * K);

  float acc0 = 0.f, acc1 = 0.f, acc2 = 0.f, acc3 = 0.f;
  #pragma unroll 4
  for (int k4 = 0; k4 < K / 4; ++k4) {
    float4 wv = w4[k4];
    float4 a;
    a = r0[k4]; acc0 += wv.x*a.x + wv.y*a.y + wv.z*a.z + wv.w*a.w;
    a = r1[k4]; acc1 += wv.x*a.x + wv.y*a.y + wv.z*a.z + wv.w*a.w;
    a = r2[k4]; acc2 += wv.x*a.x + wv.y*a.y + wv.z*a.z + wv.w*a.w;
    a = r3[k4]; acc3 += wv.x*a.x + wv.y*a.y + wv.z*a.z + wv.w*a.w;
  }
  float bb = bias[j];
  float v;
  v = acc0 + bb; if (ACT) v = tanhf(v); out[(size_t)(b0 + bg + 0) * J + j] = v;
  v = acc1 + bb; if (ACT) v = tanhf(v); out[(size_t)(b0 + bg + 1) * J + j] = v;
  v = acc2 + bb; if (ACT) v = tanhf(v); out[(size_t)(b0 + bg + 2) * J + j] = v;
  v = acc3 + bb; if (ACT) v = tanhf(v); out[(size_t)(b0 + bg + 3) * J + j] = v;
}

// ---------------------------------------------------------------------------
// d_proj = sent @ wd^T + bd   (fp32)
// M=25600, N=512, K=1024. BM=BN=128, BK=16, 256 threads, 8x8 per thread.
__launch_bounds__(256)
__global__ void k_dproj(const float* __restrict__ A, const float* __restrict__ B,
                        const float* __restrict__ bias, float* __restrict__ C) {
  __shared__ float As[16][128];
  __shared__ float Bs[16][128];
  const int m0 = blockIdx.x * 128, n0 = blockIdx.y * 128;
  const int tid = threadIdx.x;
  const int tx = tid & 15, ty = tid >> 4;

  float c[8][8] = {};

  const int r = tid & 127;
  const float* src = (tid < 128) ? (A + (size_t)(m0 + r) * Kn)
                                 : (B + (size_t)(n0 + r) * Kn);
  float (*dst)[128] = (tid < 128) ? As : Bs;

  for (int k0 = 0; k0 < Kn; k0 += 16) {
    float4 v0 = *(const float4*)(src + k0);
    float4 v1 = *(const float4*)(src + k0 + 4);
    float4 v2 = *(const float4*)(src + k0 + 8);
    float4 v3 = *(const float4*)(src + k0 + 12);
    dst[ 0][r] = v0.x; dst[ 1][r] = v0.y; dst[ 2][r] = v0.z; dst[ 3][r] = v0.w;
    dst[ 4][r] = v1.x; dst[ 5][r] = v1.y; dst[ 6][r] = v1.z; dst[ 7][r] = v1.w;
    dst[ 8][r] = v2.x; dst[ 9][r] = v2.y; dst[10][r] = v2.z; dst[11][r] = v2.w;
    dst[12][r] = v3.x; dst[13][r] = v3.y; dst[14][r] = v3.z; dst[15][r] = v3.w;
    __syncthreads();

    #pragma unroll
    for (int kk = 0; kk < 16; ++kk) {
      float4 a0 = *(const float4*)&As[kk][ty * 8];
      float4 a1 = *(const float4*)&As[kk][ty * 8 + 4];
      float4 b0 = *(const float4*)&Bs[kk][tx * 8];
      float4 b1 = *(const float4*)&Bs[kk][tx * 8 + 4];
      float av[8] = {a0.x, a0.y, a0.z, a0.w, a1.x, a1.y, a1.z, a1.w};
      float bv[8] = {b0.x, b0.y, b0.z, b0.w, b1.x, b1.y, b1.z, b1.w};
      #pragma unroll
      for (int i = 0; i < 8; ++i)
        #pragma unroll
        for (int jj = 0; jj < 8; ++jj)
          c[i][jj] += av[i] * bv[jj];
    }
    __syncthreads();
  }

  float bl[8];
  #pragma unroll
  for (int jj = 0; jj < 8; ++jj) bl[jj] = bias[n0 + tx * 8 + jj];
  #pragma unroll
  for (int i = 0; i < 8; ++i) {
    float* crow = C + (size_t)(m0 + ty * 8 + i) * Nn + n0 + tx * 8;
    float4 o0, o1;
    o0.x = c[i][0] + bl[0]; o0.y = c[i][1] + bl[1]; o0.z = c[i][2] + bl[2]; o0.w = c[i][3] + bl[3];
    o1.x = c[i][4] + bl[4]; o1.y = c[i][5] + bl[5]; o1.z = c[i][6] + bl[6]; o1.w = c[i][7] + bl[7];
    *(float4*)crow = o0;
    *(float4*)(crow + 4) = o1;
  }
}

// ---------------------------------------------------------------------------
// GRU pointwise: h = (1-z)*n + z*h
__global__ void k_gru_pw(const float* __restrict__ gx, const float* __restrict__ gh,
                         float* __restrict__ h) {
  int i = blockIdx.x * 256 + threadIdx.x;        // 65536
  int b = i >> 9, j = i & 511;
  const float* gxb = gx + (size_t)b * G3n;
  const float* ghb = gh + (size_t)b * G3n;
  float rg = 1.f / (1.f + expf(-(gxb[j] + ghb[j])));
  float zg = 1.f / (1.f + expf(-(gxb[512 + j] + ghb[512 + j])));
  float ng = tanhf(gxb[1024 + j] + rg * ghb[1024 + j]);
  h[i] = (1.f - zg) * ng + zg * h[i];
}

// ---------------------------------------------------------------------------
// score[b,l] = sum_a tanh(q[b,a] + dproj[b*L+l, a]) * ws[a] + bs ; apply mask
// one wave per (b,l); writes fp32 scratch (for argmax) + fp32 to d_out
__launch_bounds__(256)
__global__ void k_score(const float* __restrict__ dproj, const float* __restrict__ q,
                        const float* __restrict__ wsv, const float* __restrict__ bsv,
                        const int* __restrict__ mask, float* __restrict__ scoresf,
                        float* __restrict__ outScores, int t) {
  int w = blockIdx.x * 4 + (threadIdx.x >> 6);   // 0..25599
  int lane = threadIdx.x & 63;
  int b = w / Ln, l = w % Ln;
  const float4* dp4 = (const float4*)(dproj + (size_t)w * Nn);
  const float4* q4  = (const float4*)(q + (size_t)b * Nn);
  const float4* ws4 = (const float4*)wsv;

  float sum = 0.f;
  #pragma unroll
  for (int i = 0; i < 2; ++i) {
    int idx = lane + i * 64;                     // 128 float4 per row
    float4 d = dp4[idx], qq = q4[idx], wv = ws4[idx];
    sum += tanhf(qq.x + d.x) * wv.x + tanhf(qq.y + d.y) * wv.y
         + tanhf(qq.z + d.z) * wv.z + tanhf(qq.w + d.w) * wv.w;
  }
  #pragma unroll
  for (int off = 32; off > 0; off >>= 1) sum += __shfl_xor(sum, off, 64);

  if (lane == 0) {
    float v = sum + bsv[0];
    if (mask[w]) v = -1000000.0f;
    scoresf[w] = v;
    outScores[(size_t)b * (Tn * Ln) + t * Ln + l] = v;
  }
}

// ---------------------------------------------------------------------------
// per-batch argmax (first-index tie-break), update mask, gather selected row
__launch_bounds__(256)
__global__ void k_argmax(const float* __restrict__ scoresf, const float* __restrict__ sent,
                         float* __restrict__ s_row, int* __restrict__ mask,
                         float* __restrict__ outSel, int t) {
  int b = blockIdx.x;
  __shared__ int s_idx;
  int tid = threadIdx.x;
  if (tid < 64) {
    const float* sc = scoresf + (size_t)b * Ln;
    float best = -3.0e38f; int bi = 0;
    for (int l = tid; l < Ln; l += 64) {
      float v = sc[l];
      if (v > best) { best = v; bi = l; }        // increasing l: strict > keeps first
    }
    #pragma unroll
    for (int off = 32; off > 0; off >>= 1) {
      float ov = __shfl_down(best, off, 64);
      int   oi = __shfl_down(bi,   off, 64);
      if (ov > best || (ov == best && oi < bi)) { best = ov; bi = oi; }
    }
    if (tid == 0) s_idx = bi;
  }
  __syncthreads();
  int idx = s_idx;
  const float* src = sent + ((size_t)b * Ln + idx) * D2n;
  float* dstp = s_row + (size_t)b * D2n;
  int k = tid * 4;                               // 256 threads x 4 = 1024
  *(float4*)(dstp + k) = *(const float4*)(src + k);
  if (tid == 0) {
    mask[b * Ln + idx] = 1;
    outSel[(size_t)b * Tn + t] = (float)idx;
  }
}

// ---------------------------------------------------------------------------
extern "C" void kernel_launch(void* const* d_in, const int* in_sizes, int n_in,
                              void* d_out, int out_size, void* d_ws, size_t ws_size,
                              hipStream_t stream) {
  const float* sent = (const float*)d_in[0];
  const float* h0_w = (const float*)d_in[1];
  const float* h0_b = (const float*)d_in[2];
  const float* w_ih = (const float*)d_in[3];
  const float* w_hh = (const float*)d_in[4];
  const float* b_ih = (const float*)d_in[5];
  const float* b_hh = (const float*)d_in[6];
  const float* wq   = (const float*)d_in[7];
  const float* bq   = (const float*)d_in[8];
  const float* wd   = (const float*)d_in[9];
  const float* bd   = (const float*)d_in[10];
  const float* wsv  = (const float*)d_in[11];
  const float* bsv  = (const float*)d_in[12];

  float* wsf     = (float*)d_ws;
  float* d_proj  = wsf;                       // 25600*512 = 13107200
  float* s_row   = d_proj + 13107200;         // 128*1024
  float* h       = s_row + 131072;            // 128*512
  float* gx      = h + 65536;                 // 128*1536
  float* gh      = gx + 196608;               // 128*1536
  float* lastb   = gh + 196608;               // 128*512
  float* q       = lastb + 65536;             // 128*512
  float* scoresf = q + 65536;                 // 128*200
  int*   mask    = (int*)(scoresf + 25600);   // 128*200 ints

  float* outScores = (float*)d_out;                       // (B, T, L) fp32
  float* outSel    = outScores + (size_t)Bn * Tn * Ln;    // (B, T) fp32, offset 76800

  hipMemsetAsync(s_row, 0, 131072 * sizeof(float), stream);       // s_prev(t=0) = 0
  hipMemsetAsync(mask, 0, 25600 * sizeof(int), stream);

  k_gather_lastb<<<256, 256, 0, stream>>>(sent, lastb);
  k_small_gemm<512, 1><<<dim3(8, 8), 256, 0, stream>>>(lastb, h0_w, h0_b, h, 512);
  k_dproj<<<dim3(200, 4), 256, 0, stream>>>(sent, wd, bd, d_proj);

  for (int t = 0; t < Tn; ++t) {
    k_small_gemm<1024, 0><<<dim3(24, 8), 256, 0, stream>>>(s_row, w_ih, b_ih, gx, G3n);
    k_small_gemm<512, 0><<<dim3(24, 8), 256, 0, stream>>>(h, w_hh, b_hh, gh, G3n);
    k_gru_pw<<<256, 256, 0, stream>>>(gx, gh, h);
    k_small_gemm<512, 0><<<dim3(8, 8), 256, 0, stream>>>(h, wq, bq, q, 512);
    k_score<<<6400, 256, 0, stream>>>(d_proj, q, wsv, bsv, mask, scoresf, outScores, t);
    k_argmax<<<128, 256, 0, stream>>>(scoresf, sent, s_row, mask, outSel, t);
  }
}

// Round 4
// 613.086 us; speedup vs baseline: 1.4068x; 1.4068x over previous
//
#include <hip/hip_runtime.h>
#include <hip/hip_bf16.h>

// Problem constants
constexpr int Bn  = 128;   // batch
constexpr int Ln  = 200;   // sentences
constexpr int D2n = 1024;  // 2*SH
constexpr int G3n = 1536;  // 3*EH
constexpr int Tn  = 3;
constexpr int Nn  = 512;   // A (attention dim) == d_proj cols
constexpr int Kn  = 1024;  // d_proj K

typedef unsigned short ushort;
typedef float f32x4 __attribute__((ext_vector_type(4)));
typedef __bf16 bf16x8 __attribute__((ext_vector_type(8)));

__device__ __forceinline__ ushort f2bf(float f) {   // RNE float->bf16
  unsigned u = __float_as_uint(f);
  unsigned r = (u + 0x7fffu + ((u >> 16) & 1u)) >> 16;
  return (ushort)r;
}
__device__ __forceinline__ float bf2f(ushort h) {
  return __uint_as_float(((unsigned)h) << 16);
}

// ---------------------------------------------------------------------------
// gather last_back = sent[:, 0, 512:1024]
__global__ void k_gather_lastb(const float* __restrict__ sent, float* __restrict__ lastb) {
  int i = blockIdx.x * 256 + threadIdx.x;        // 65536 = 128*512
  int b = i >> 9, k = i & 511;
  lastb[i] = sent[(size_t)b * (Ln * D2n) + 512 + k];
}

// ---------------------------------------------------------------------------
// split W (fp32, N elements) into hi/lo bf16
__global__ void k_splitW(const float* __restrict__ W, ushort* __restrict__ hi,
                         ushort* __restrict__ lo) {
  int i = blockIdx.x * 256 + threadIdx.x;        // element/4
  float4 v = ((const float4*)W)[i];
  ushort4 h, l;
  h.x = f2bf(v.x); l.x = f2bf(v.x - bf2f(h.x));
  h.y = f2bf(v.y); l.y = f2bf(v.y - bf2f(h.y));
  h.z = f2bf(v.z); l.z = f2bf(v.z - bf2f(h.z));
  h.w = f2bf(v.w); l.w = f2bf(v.w - bf2f(h.w));
  ((ushort4*)hi)[i] = h;
  ((ushort4*)lo)[i] = l;
}

// ---------------------------------------------------------------------------
// small GEMM: out[b,j] = act(bias[j] + sum_k in[b,k] * W[j,k])
template<int K, int ACT>
__launch_bounds__(256)
__global__ void k_small_gemm(const float* __restrict__ in, const float* __restrict__ W,
                             const float* __restrict__ bias, float* __restrict__ out, int J) {
  __shared__ float s[16 * K];
  const int b0 = blockIdx.y * 16;
  const int jl = threadIdx.x & 63;
  const int j  = blockIdx.x * 64 + jl;
  const int bg = (threadIdx.x >> 6) * 4;         // 0,4,8,12

  const float4* inp4 = (const float4*)(in + (size_t)b0 * K);
  float4* s4 = (float4*)s;
  for (int i = threadIdx.x; i < 4 * K; i += 256) s4[i] = inp4[i];
  __syncthreads();

  const float4* w4 = (const float4*)(W + (size_t)j * K);
  const float4* r0 = (const float4*)(s + (size_t)(bg + 0) * K);
  const float4* r1 = (const float4*)(s + (size_t)(bg + 1) * K);
  const float4* r2 = (const float4*)(s + (size_t)(bg + 2) * K);
  const float4* r3 = (const float4*)(s + (size_t)(bg + 3) * K);

  float acc0 = 0.f, acc1 = 0.f, acc2 = 0.f, acc3 = 0.f;
  #pragma unroll 4
  for (int k4 = 0; k4 < K / 4; ++k4) {
    float4 wv = w4[k4];
    float4 a;
    a = r0[k4]; acc0 += wv.x*a.x + wv.y*a.y + wv.z*a.z + wv.w*a.w;
    a = r1[k4]; acc1 += wv.x*a.x + wv.y*a.y + wv.z*a.z + wv.w*a.w;
    a = r2[k4]; acc2 += wv.x*a.x + wv.y*a.y + wv.z*a.z + wv.w*a.w;
    a = r3[k4]; acc3 += wv.x*a.x + wv.y*a.y + wv.z*a.z + wv.w*a.w;
  }
  float bb = bias[j];
  float v;
  v = acc0 + bb; if (ACT) v = tanhf(v); out[(size_t)(b0 + bg + 0) * J + j] = v;
  v = acc1 + bb; if (ACT) v = tanhf(v); out[(size_t)(b0 + bg + 1) * J + j] = v;
  v = acc2 + bb; if (ACT) v = tanhf(v); out[(size_t)(b0 + bg + 2) * J + j] = v;
  v = acc3 + bb; if (ACT) v = tanhf(v); out[(size_t)(b0 + bg + 3) * J + j] = v;
}

// ---------------------------------------------------------------------------
// d_proj = sent @ wd^T + bd  via split-bf16 MFMA (3 mfma per tile, fp32 acc)
// M=25600 N=512 K=1024. Block 128x128, BK=32, 256 thr = 4 waves of 64x64.
constexpr int LDW = 40;   // padded LDS row (shorts): 80 B = 16B-aligned, conflict-free
__launch_bounds__(256)
__global__ void k_dproj_mfma(const float* __restrict__ A, const ushort* __restrict__ Whi,
                             const ushort* __restrict__ Wlo, const float* __restrict__ bias,
                             float* __restrict__ C) {
  __shared__ __align__(16) ushort Ah[128][LDW];
  __shared__ __align__(16) ushort Al[128][LDW];
  __shared__ __align__(16) ushort Bh[128][LDW];
  __shared__ __align__(16) ushort Bl[128][LDW];

  const int m0 = blockIdx.x * 128, n0 = blockIdx.y * 128;
  const int tid  = threadIdx.x;
  const int wave = tid >> 6, lane = tid & 63;
  const int wy = (wave >> 1) * 64, wx = (wave & 1) * 64;
  const int lm = lane & 15, lq = lane >> 4;      // tile row/col, quad

  const int sr   = tid >> 1;                     // staging row 0..127
  const int sk   = (tid & 1) * 16;               // staging k-offset 0/16

  f32x4 acc[4][4] = {};

  const float* Arow = A + (size_t)(m0 + sr) * Kn + sk;
  const ushort* Bhrow = Whi + (size_t)(n0 + sr) * Kn + sk;
  const ushort* Blrow = Wlo + (size_t)(n0 + sr) * Kn + sk;

  for (int k0 = 0; k0 < Kn; k0 += 32) {
    // ---- stage A (fp32 -> hi/lo bf16 on the fly): 16 floats per thread
    #pragma unroll
    for (int i = 0; i < 4; ++i) {
      float4 v = *(const float4*)(Arow + k0 + i * 4);
      ushort4 h, l;
      h.x = f2bf(v.x); l.x = f2bf(v.x - bf2f(h.x));
      h.y = f2bf(v.y); l.y = f2bf(v.y - bf2f(h.y));
      h.z = f2bf(v.z); l.z = f2bf(v.z - bf2f(h.z));
      h.w = f2bf(v.w); l.w = f2bf(v.w - bf2f(h.w));
      *(ushort4*)&Ah[sr][sk + i * 4] = h;
      *(ushort4*)&Al[sr][sk + i * 4] = l;
    }
    // ---- stage B (pre-split bf16): 16 shorts per thread per buffer
    #pragma unroll
    for (int i = 0; i < 2; ++i) {
      *(int4*)&Bh[sr][sk + i * 8] = *(const int4*)(Bhrow + k0 + i * 8);
      *(int4*)&Bl[sr][sk + i * 8] = *(const int4*)(Blrow + k0 + i * 8);
    }
    __syncthreads();

    bf16x8 ah[4], al[4], bh[4], bl[4];
    #pragma unroll
    for (int mi = 0; mi < 4; ++mi) {
      ah[mi] = *(const bf16x8*)&Ah[wy + mi * 16 + lm][lq * 8];
      al[mi] = *(const bf16x8*)&Al[wy + mi * 16 + lm][lq * 8];
    }
    #pragma unroll
    for (int ni = 0; ni < 4; ++ni) {
      bh[ni] = *(const bf16x8*)&Bh[wx + ni * 16 + lm][lq * 8];
      bl[ni] = *(const bf16x8*)&Bl[wx + ni * 16 + lm][lq * 8];
    }
    #pragma unroll
    for (int mi = 0; mi < 4; ++mi)
      #pragma unroll
      for (int ni = 0; ni < 4; ++ni) {
        acc[mi][ni] = __builtin_amdgcn_mfma_f32_16x16x32_bf16(ah[mi], bh[ni], acc[mi][ni], 0, 0, 0);
        acc[mi][ni] = __builtin_amdgcn_mfma_f32_16x16x32_bf16(ah[mi], bl[ni], acc[mi][ni], 0, 0, 0);
        acc[mi][ni] = __builtin_amdgcn_mfma_f32_16x16x32_bf16(al[mi], bh[ni], acc[mi][ni], 0, 0, 0);
      }
    __syncthreads();
  }

  // epilogue: D[row=quad*4+r][col=lane&15] per 16x16 tile
  #pragma unroll
  for (int ni = 0; ni < 4; ++ni) {
    int col = n0 + wx + ni * 16 + lm;
    float bb = bias[col];
    #pragma unroll
    for (int mi = 0; mi < 4; ++mi) {
      int rbase = m0 + wy + mi * 16 + lq * 4;
      #pragma unroll
      for (int r = 0; r < 4; ++r)
        C[(size_t)(rbase + r) * Nn + col] = acc[mi][ni][r] + bb;
    }
  }
}

// ---------------------------------------------------------------------------
// GRU pointwise: h = (1-z)*n + z*h
__global__ void k_gru_pw(const float* __restrict__ gx, const float* __restrict__ gh,
                         float* __restrict__ h) {
  int i = blockIdx.x * 256 + threadIdx.x;        // 65536
  int b = i >> 9, j = i & 511;
  const float* gxb = gx + (size_t)b * G3n;
  const float* ghb = gh + (size_t)b * G3n;
  float rg = 1.f / (1.f + expf(-(gxb[j] + ghb[j])));
  float zg = 1.f / (1.f + expf(-(gxb[512 + j] + ghb[512 + j])));
  float ng = tanhf(gxb[1024 + j] + rg * ghb[1024 + j]);
  h[i] = (1.f - zg) * ng + zg * h[i];
}

// ---------------------------------------------------------------------------
// score[b,l] = sum_a tanh(q[b,a] + dproj[b*L+l, a]) * ws[a] + bs ; apply mask
__launch_bounds__(256)
__global__ void k_score(const float* __restrict__ dproj, const float* __restrict__ q,
                        const float* __restrict__ wsv, const float* __restrict__ bsv,
                        const int* __restrict__ mask, float* __restrict__ scoresf,
                        float* __restrict__ outScores, int t) {
  int w = blockIdx.x * 4 + (threadIdx.x >> 6);   // 0..25599
  int lane = threadIdx.x & 63;
  int b = w / Ln, l = w % Ln;
  const float4* dp4 = (const float4*)(dproj + (size_t)w * Nn);
  const float4* q4  = (const float4*)(q + (size_t)b * Nn);
  const float4* ws4 = (const float4*)wsv;

  float sum = 0.f;
  #pragma unroll
  for (int i = 0; i < 2; ++i) {
    int idx = lane + i * 64;                     // 128 float4 per row
    float4 d = dp4[idx], qq = q4[idx], wv = ws4[idx];
    sum += tanhf(qq.x + d.x) * wv.x + tanhf(qq.y + d.y) * wv.y
         + tanhf(qq.z + d.z) * wv.z + tanhf(qq.w + d.w) * wv.w;
  }
  #pragma unroll
  for (int off = 32; off > 0; off >>= 1) sum += __shfl_xor(sum, off, 64);

  if (lane == 0) {
    float v = sum + bsv[0];
    if (mask[w]) v = -1000000.0f;
    scoresf[w] = v;
    outScores[(size_t)b * (Tn * Ln) + t * Ln + l] = v;
  }
}

// ---------------------------------------------------------------------------
// per-batch argmax (first-index tie-break), update mask, gather selected row
__launch_bounds__(256)
__global__ void k_argmax(const float* __restrict__ scoresf, const float* __restrict__ sent,
                         float* __restrict__ s_row, int* __restrict__ mask,
                         float* __restrict__ outSel, int t) {
  int b = blockIdx.x;
  __shared__ int s_idx;
  int tid = threadIdx.x;
  if (tid < 64) {
    const float* sc = scoresf + (size_t)b * Ln;
    float best = -3.0e38f; int bi = 0;
    for (int l = tid; l < Ln; l += 64) {
      float v = sc[l];
      if (v > best) { best = v; bi = l; }        // increasing l: strict > keeps first
    }
    #pragma unroll
    for (int off = 32; off > 0; off >>= 1) {
      float ov = __shfl_down(best, off, 64);
      int   oi = __shfl_down(bi,   off, 64);
      if (ov > best || (ov == best && oi < bi)) { best = ov; bi = oi; }
    }
    if (tid == 0) s_idx = bi;
  }
  __syncthreads();
  int idx = s_idx;
  const float* src = sent + ((size_t)b * Ln + idx) * D2n;
  float* dstp = s_row + (size_t)b * D2n;
  int k = tid * 4;                               // 256 threads x 4 = 1024
  *(float4*)(dstp + k) = *(const float4*)(src + k);
  if (tid == 0) {
    mask[b * Ln + idx] = 1;
    outSel[(size_t)b * Tn + t] = (float)idx;
  }
}

// ---------------------------------------------------------------------------
extern "C" void kernel_launch(void* const* d_in, const int* in_sizes, int n_in,
                              void* d_out, int out_size, void* d_ws, size_t ws_size,
                              hipStream_t stream) {
  const float* sent = (const float*)d_in[0];
  const float* h0_w = (const float*)d_in[1];
  const float* h0_b = (const float*)d_in[2];
  const float* w_ih = (const float*)d_in[3];
  const float* w_hh = (const float*)d_in[4];
  const float* b_ih = (const float*)d_in[5];
  const float* b_hh = (const float*)d_in[6];
  const float* wq   = (const float*)d_in[7];
  const float* bq   = (const float*)d_in[8];
  const float* wd   = (const float*)d_in[9];
  const float* bd   = (const float*)d_in[10];
  const float* wsv  = (const float*)d_in[11];
  const float* bsv  = (const float*)d_in[12];

  float* wsf     = (float*)d_ws;
  float* d_proj  = wsf;                       // 25600*512 = 13107200
  float* s_row   = d_proj + 13107200;         // 128*1024
  float* h       = s_row + 131072;            // 128*512
  float* gx      = h + 65536;                 // 128*1536
  float* gh      = gx + 196608;               // 128*1536
  float* lastb   = gh + 196608;               // 128*512
  float* q       = lastb + 65536;             // 128*512
  float* scoresf = q + 65536;                 // 128*200
  int*   mask    = (int*)(scoresf + 25600);   // 128*200 ints
  ushort* Whi    = (ushort*)(mask + 25600);   // 512*1024 shorts
  ushort* Wlo    = Whi + 524288;              // 512*1024 shorts

  float* outScores = (float*)d_out;                       // (B, T, L) fp32
  float* outSel    = outScores + (size_t)Bn * Tn * Ln;    // (B, T) fp32

  hipMemsetAsync(s_row, 0, 131072 * sizeof(float), stream);       // s_prev(t=0) = 0
  hipMemsetAsync(mask, 0, 25600 * sizeof(int), stream);

  k_gather_lastb<<<256, 256, 0, stream>>>(sent, lastb);
  k_small_gemm<512, 1><<<dim3(8, 8), 256, 0, stream>>>(lastb, h0_w, h0_b, h, 512);
  k_splitW<<<512, 256, 0, stream>>>(wd, Whi, Wlo);        // 512*1024/4 = 131072 float4
  k_dproj_mfma<<<dim3(200, 4), 256, 0, stream>>>(sent, Whi, Wlo, bd, d_proj);

  for (int t = 0; t < Tn; ++t) {
    k_small_gemm<1024, 0><<<dim3(24, 8), 256, 0, stream>>>(s_row, w_ih, b_ih, gx, G3n);
    k_small_gemm<512, 0><<<dim3(24, 8), 256, 0, stream>>>(h, w_hh, b_hh, gh, G3n);
    k_gru_pw<<<256, 256, 0, stream>>>(gx, gh, h);
    k_small_gemm<512, 0><<<dim3(8, 8), 256, 0, stream>>>(h, wq, bq, q, 512);
    k_score<<<6400, 256, 0, stream>>>(d_proj, q, wsv, bsv, mask, scoresf, outScores, t);
    k_argmax<<<128, 256, 0, stream>>>(scoresf, sent, s_row, mask, outSel, t);
  }
}